// Round 1
// baseline (719.955 us; speedup 1.0000x reference)
//
#include <hip/hip_runtime.h>

#define SCAN_CHUNK 1024

// ---------------- CSR build ----------------

__global__ void hist_kernel(const int* __restrict__ dst, int* __restrict__ cnt, int E) {
    int i = blockIdx.x * blockDim.x + threadIdx.x;
    int stride = gridDim.x * blockDim.x;
    for (; i < E; i += stride) atomicAdd(&cnt[dst[i]], 1);
}

__global__ void block_sum_kernel(const int* __restrict__ cnt, int* __restrict__ partials, int n) {
    __shared__ int sdata[256];
    int base = blockIdx.x * SCAN_CHUNK;
    int sum = 0;
    for (int i = threadIdx.x; i < SCAN_CHUNK; i += 256) {
        int idx = base + i;
        sum += (idx < n) ? cnt[idx] : 0;
    }
    sdata[threadIdx.x] = sum;
    __syncthreads();
    for (int s = 128; s > 0; s >>= 1) {
        if (threadIdx.x < s) sdata[threadIdx.x] += sdata[threadIdx.x + s];
        __syncthreads();
    }
    if (threadIdx.x == 0) partials[blockIdx.x] = sdata[0];
}

__global__ void scan_partials_kernel(int* __restrict__ partials, int nb,
                                     int* __restrict__ row_ptr, int n) {
    if (threadIdx.x == 0 && blockIdx.x == 0) {
        int acc = 0;
        for (int i = 0; i < nb; i++) { int v = partials[i]; partials[i] = acc; acc += v; }
        row_ptr[n] = acc;  // total edge count
    }
}

__global__ void scan_write_kernel(const int* __restrict__ cnt, const int* __restrict__ partials,
                                  int* __restrict__ row_ptr, int n) {
    __shared__ int sdata[256];
    int base = blockIdx.x * SCAN_CHUNK;
    int tbase = base + threadIdx.x * 4;
    int vals[4];
    int tsum = 0;
    #pragma unroll
    for (int j = 0; j < 4; j++) {
        int idx = tbase + j;
        vals[j] = (idx < n) ? cnt[idx] : 0;
        tsum += vals[j];
    }
    sdata[threadIdx.x] = tsum;
    __syncthreads();
    // Hillis-Steele inclusive scan over 256 per-thread sums
    for (int s = 1; s < 256; s <<= 1) {
        int v = (threadIdx.x >= s) ? sdata[threadIdx.x - s] : 0;
        __syncthreads();
        sdata[threadIdx.x] += v;
        __syncthreads();
    }
    int excl = (threadIdx.x == 0) ? 0 : sdata[threadIdx.x - 1];
    int offset = partials[blockIdx.x] + excl;
    #pragma unroll
    for (int j = 0; j < 4; j++) {
        int idx = tbase + j;
        if (idx < n) row_ptr[idx] = offset;
        offset += vals[j];
    }
}

__global__ void scatter_kernel(const int* __restrict__ src, const int* __restrict__ dst,
                               const int* __restrict__ row_ptr, int* __restrict__ fill,
                               int* __restrict__ srcidx, int E) {
    int e = blockIdx.x * blockDim.x + threadIdx.x;
    int stride = gridDim.x * blockDim.x;
    for (; e < E; e += stride) {
        int d = dst[e];
        int pos = atomicAdd(&fill[d], 1);
        srcidx[row_ptr[d] + pos] = src[e];
    }
}

__global__ void dinv_kernel(const int* __restrict__ row_ptr, float* __restrict__ dinv, int n) {
    int i = blockIdx.x * blockDim.x + threadIdx.x;
    if (i < n) {
        int deg = row_ptr[i + 1] - row_ptr[i] + 1;  // +1 self-loop
        dinv[i] = rsqrtf((float)deg);
    }
}

// ---------------- dense transform: g[r][c] = dinv[r] * sum_k in[r][k]*W[k][c] ----------------

__global__ __launch_bounds__(256) void transform_kernel(const float* __restrict__ in,
                                                        const float* __restrict__ W,
                                                        const float* __restrict__ dinv,
                                                        float* __restrict__ g, int n) {
    __shared__ float Ws[64 * 64];
    for (int i = threadIdx.x; i < 64 * 64; i += 256) Ws[i] = W[i];
    __syncthreads();
    int lane = threadIdx.x & 63;
    int wave = (blockIdx.x * 256 + threadIdx.x) >> 6;
    int nwaves = gridDim.x * 4;
    for (int r = wave; r < n; r += nwaves) {
        float xv = in[r * 64 + lane];
        float acc = 0.f;
        #pragma unroll
        for (int k = 0; k < 64; k++) {
            float xk = __shfl(xv, k, 64);
            acc = fmaf(xk, Ws[k * 64 + lane], acc);
        }
        g[r * 64 + lane] = acc * dinv[r];
    }
}

// ---------------- aggregate: out[i] = dinv[i]*(g[i] + sum_{j in N(i)} g[j]) + b ----------------

__global__ __launch_bounds__(256) void aggregate_kernel(const float* __restrict__ g,
                                                        const int* __restrict__ row_ptr,
                                                        const int* __restrict__ srcidx,
                                                        const float* __restrict__ dinv,
                                                        const float* __restrict__ b,
                                                        float* __restrict__ out, int n, int relu) {
    int lane = threadIdx.x & 63;
    int node = (blockIdx.x * 256 + threadIdx.x) >> 6;
    if (node >= n) return;
    node = __builtin_amdgcn_readfirstlane(node);  // wave-uniform -> scalar loads for indices
    int beg = row_ptr[node];
    int end = row_ptr[node + 1];
    float acc = g[node * 64 + lane];  // self-loop term (g already has dinv factor)
    int e = beg;
    for (; e + 4 <= end; e += 4) {
        int s0 = srcidx[e + 0], s1 = srcidx[e + 1], s2 = srcidx[e + 2], s3 = srcidx[e + 3];
        float v0 = g[s0 * 64 + lane];
        float v1 = g[s1 * 64 + lane];
        float v2 = g[s2 * 64 + lane];
        float v3 = g[s3 * 64 + lane];
        acc += (v0 + v1) + (v2 + v3);
    }
    for (; e < end; ++e) acc += g[srcidx[e] * 64 + lane];
    float o = fmaf(dinv[node], acc, b[lane]);
    out[node * 64 + lane] = relu ? fmaxf(o, 0.f) : o;
}

extern "C" void kernel_launch(void* const* d_in, const int* in_sizes, int n_in,
                              void* d_out, int out_size, void* d_ws, size_t ws_size,
                              hipStream_t stream) {
    const float* x  = (const float*)d_in[0];
    const int*   ei = (const int*)d_in[1];
    const float* W1 = (const float*)d_in[2];
    const float* b1 = (const float*)d_in[3];
    const float* W2 = (const float*)d_in[4];
    const float* b2 = (const float*)d_in[5];
    float* out = (float*)d_out;

    const int n = in_sizes[0] / 64;      // 100000
    const int E = in_sizes[1] / 2;       // 3200000
    const int* src = ei;
    const int* dst = ei + E;

    // workspace carve-up (256B aligned)
    char* ws = (char*)d_ws;
    size_t off = 0;
    auto carve = [&](size_t bytes) { char* p = ws + off; off = (off + bytes + 255) & ~(size_t)255; return p; };
    int*   cnt      = (int*)  carve((size_t)n * 4);          // histogram, then fill cursor
    int*   row_ptr  = (int*)  carve((size_t)(n + 1) * 4);
    int*   partials = (int*)  carve(4096);
    float* dinv     = (float*)carve((size_t)n * 4);
    int*   srcidx   = (int*)  carve((size_t)E * 4);
    float* g        = (float*)carve((size_t)n * 64 * 4);     // scaled features

    const int nb = (n + SCAN_CHUNK - 1) / SCAN_CHUNK;        // 98

    // ---- CSR build (shared by both layers) ----
    hipMemsetAsync(cnt, 0, (size_t)n * 4, stream);
    hist_kernel<<<4096, 256, 0, stream>>>(dst, cnt, E);
    block_sum_kernel<<<nb, 256, 0, stream>>>(cnt, partials, n);
    scan_partials_kernel<<<1, 64, 0, stream>>>(partials, nb, row_ptr, n);
    scan_write_kernel<<<nb, 256, 0, stream>>>(cnt, partials, row_ptr, n);
    hipMemsetAsync(cnt, 0, (size_t)n * 4, stream);
    scatter_kernel<<<4096, 256, 0, stream>>>(src, dst, row_ptr, cnt, srcidx, E);
    dinv_kernel<<<(n + 255) / 256, 256, 0, stream>>>(row_ptr, dinv, n);

    const int agg_grid = (n * 64 + 255) / 256;               // one wave per node

    // ---- layer 1: g = (x@W1)*dinv ; h1 = relu(dinv*(agg(g)+g)+b1) -> stored in d_out ----
    transform_kernel<<<1024, 256, 0, stream>>>(x, W1, dinv, g, n);
    aggregate_kernel<<<agg_grid, 256, 0, stream>>>(g, row_ptr, srcidx, dinv, b1, out, n, 1);

    // ---- layer 2: g = (h1@W2)*dinv ; out = dinv*(agg(g)+g)+b2 ----
    transform_kernel<<<1024, 256, 0, stream>>>(out, W2, dinv, g, n);
    aggregate_kernel<<<agg_grid, 256, 0, stream>>>(g, row_ptr, srcidx, dinv, b2, out, n, 0);
}